// Round 6
// baseline (135.861 us; speedup 1.0000x reference)
//
#include <hip/hip_runtime.h>

#define Hh 96
#define Ww 96
#define CIN 64
#define COUT 64
#define BATCH 8
#define HW 9216           // Hh*Ww
#define NOFF 18           // 2*K*K

typedef __attribute__((ext_vector_type(8))) short bf16x8;
typedef __attribute__((ext_vector_type(4))) float f32x4;

__device__ inline ushort f2bf(float f) {
  union { float f; uint u; } v; v.f = f;
  uint u = v.u;
  u += 0x7FFF + ((u >> 16) & 1);     // RNE
  return (ushort)(u >> 16);
}
__device__ inline float bflo(uint u) {       // low bf16 -> f32
  union { uint u; float f; } v; v.u = u << 16; return v.f;
}
__device__ inline float bfhi(uint u) {       // high bf16 -> f32
  union { uint u; float f; } v; v.u = u & 0xFFFF0000u; return v.f;
}
__device__ inline uint pack_rne(float a, float b) {  // {bf(a), bf(b)} -> u32
  union { float f; uint u; } x, y; x.f = a; y.f = b;
  uint ua = x.u + (0x7FFFu + ((x.u >> 16) & 1));
  uint ub = y.u + (0x7FFFu + ((y.u >> 16) & 1));
  return (ua >> 16) | (ub & 0xFFFF0000u);
}

// ---------------------------------------------------------------------------
// K0: transpose x (NCHW f32) -> xt (NHWC bf16) via padded LDS tile, + pack
// weights (wtb, wob) in low blocks.
// ---------------------------------------------------------------------------
__global__ __launch_bounds__(256) void k_xt(
    const float* __restrict__ x, const float* __restrict__ w_def,
    const float* __restrict__ w_off, ushort* __restrict__ xt,
    ushort* __restrict__ wtb, ushort* __restrict__ wob)
{
  __shared__ float tile[64][65];
  int tid = threadIdx.x;
  int blk = blockIdx.x;

  if (blk < 9) {            // wtb[k][o][c] = bf16(w_def[o][c][k]), k = blk
    for (int i = tid; i < 4096; i += 256) {
      int o = i >> 6, c = i & 63;
      wtb[blk * 4096 + i] = f2bf(w_def[(o * 64 + c) * 9 + blk]);
    }
  } else if (blk < 25 && blk >= 16) {   // wob[k][n(32)][c], k = blk-16
    int k = blk - 16;
    for (int i = tid; i < 2048; i += 256) {
      int n = i >> 6, c = i & 63;
      wob[k * 2048 + i] = (n < NOFF) ? f2bf(w_off[(n * 64 + c) * 9 + k]) : (ushort)0;
    }
  }

  int b = blk / 144;
  int pbase = (blk - b * 144) * 64;
  int wave = tid >> 6, lane = tid & 63;
  const float* xp = x + (size_t)b * CIN * HW + pbase;
  #pragma unroll
  for (int i = 0; i < 16; ++i) {
    int c = wave * 16 + i;
    tile[lane][c] = xp[(size_t)c * HW + lane];    // coalesced 256B reads
  }
  __syncthreads();
  ushort* xo = xt + ((size_t)b * HW + pbase) * 64;
  #pragma unroll
  for (int i = 0; i < 16; ++i) {
    int p = wave * 16 + i;
    xo[(size_t)p * 64 + lane] = f2bf(tile[p][lane]);  // coalesced 128B writes
  }
}

// gather set for one tap (one channel-half: 4 corners x 16B)
struct TapG {
  uint4 c00, c01, c10, c11;
  float w00, w01, w10, w11;
};

// ---------------------------------------------------------------------------
// K1: FUSED offset-conv + deformable sampling + MFMA + BN partials.
// Block = 512 threads (8 waves), 64 px x 64 out.  Wave w: pixel-group
// pg = w&3 (16 px), channel-half kh = w>>2 (32 of 64 input channels).
// Phase A: offset conv partials over K=32 per wave; summed via LDS.
// Phase B: deform loop over this wave's 32 channels, 2-tap gather pipeline;
// epilogue combines kh partials through LDS (aliased with transpose buffer).
// ---------------------------------------------------------------------------
__global__ __launch_bounds__(512, 6) void k_deform(
    const ushort* __restrict__ xt, const ushort* __restrict__ wtb,
    const ushort* __restrict__ wob, const float* __restrict__ b_off,
    const float* __restrict__ b_def, float* __restrict__ out,
    float* __restrict__ parts)
{
  __shared__ float lds_f[4352];          // alias: P[4][64][17] then T[64][68]
  __shared__ float red[512];
  __shared__ float offs_lds[8][18][17];  // per-wave offset-conv partials

  int tid = threadIdx.x;
  int bid = blockIdx.x;
  int blk = (bid & 7) * 144 + (bid >> 3);   // XCD-batch swizzle: batch = XCD
  int b = blk / 144;
  int pbase = (blk - b * 144) * 64;
  int wave = tid >> 6, lane = tid & 63;
  int pg = wave & 3, kh = wave >> 2;
  int m = lane & 15, hi = lane >> 4;
  int p_pix = pbase + pg * 16 + m;
  int h = p_pix / Ww, w = p_pix - (p_pix / Ww) * Ww;
  int chof = kh * 32 + hi * 8;              // this lane's channel slice

  const ushort* xb = xt + ((size_t)b * HW) * 64;

  // ---------------- Phase A: offset conv (K=32 partial per wave) -----------
  {
    f32x4 oacc[2];
    oacc[0] = (f32x4){0.f, 0.f, 0.f, 0.f};
    oacc[1] = (f32x4){0.f, 0.f, 0.f, 0.f};

    #pragma unroll
    for (int k = 0; k < 9; ++k) {
      int ky = k / 3, kx = k - ky * 3;
      int yy = h + ky - 1, xx = w + kx - 1;
      bool valid = (yy >= 0 && yy < Hh && xx >= 0 && xx < Ww);
      int pos = min(max(yy, 0), Hh - 1) * Ww + min(max(xx, 0), Ww - 1);
      const ushort* pp = xb + (size_t)pos * 64 + chof;
      bf16x8 a0 = *(const bf16x8*)pp;
      if (!valid) a0 = (bf16x8)0;

      const ushort* wk = wob + (size_t)k * 2048 + chof;
      #pragma unroll
      for (int nt = 0; nt < 2; ++nt) {
        bf16x8 b0 = *(const bf16x8*)(wk + (nt * 16 + m) * 64);
        oacc[nt] = __builtin_amdgcn_mfma_f32_16x16x32_bf16(a0, b0, oacc[nt], 0, 0, 0);
      }
    }

    #pragma unroll
    for (int nt = 0; nt < 2; ++nt) {
      int j = nt * 16 + m;
      if (j < NOFF) {
        float bo = (kh == 0) ? b_off[j] : 0.f;   // bias added exactly once
        #pragma unroll
        for (int r = 0; r < 4; ++r)
          offs_lds[wave][j][hi * 4 + r] = oacc[nt][r] + bo;
      }
    }
  }
  __syncthreads();

  // ---------------- Phase B: deform loop, 2-tap gather pipeline ------------
  f32x4 acc[4];
  #pragma unroll
  for (int nt = 0; nt < 4; ++nt) acc[nt] = (f32x4){0.f, 0.f, 0.f, 0.f};

  auto tap_issue = [&](int k, TapG& t) {
    float dy = offs_lds[pg][2 * k][m] + offs_lds[pg + 4][2 * k][m];
    float dx = offs_lds[pg][2 * k + 1][m] + offs_lds[pg + 4][2 * k + 1][m];
    int ky = k / 3, kx = k - ky * 3;
    float py = (float)(h + ky - 1) + dy;
    float px = (float)(w + kx - 1) + dx;
    float y0f = floorf(py), x0f = floorf(px);
    float ly = py - y0f, lx = px - x0f;
    int y0 = (int)y0f, x0 = (int)x0f;
    int y1 = y0 + 1, x1 = x0 + 1;
    float fy0 = (y0 >= 0 && y0 < Hh) ? 1.f : 0.f;
    float fy1 = (y1 >= 0 && y1 < Hh) ? 1.f : 0.f;
    float fx0 = (x0 >= 0 && x0 < Ww) ? 1.f : 0.f;
    float fx1 = (x1 >= 0 && x1 < Ww) ? 1.f : 0.f;
    int cy0 = min(max(y0, 0), Hh - 1), cy1 = min(max(y1, 0), Hh - 1);
    int cx0 = min(max(x0, 0), Ww - 1), cx1 = min(max(x1, 0), Ww - 1);
    size_t o00 = (size_t)(cy0 * Ww + cx0) * 64;
    size_t o01 = (size_t)(cy0 * Ww + cx1) * 64;
    size_t o10 = (size_t)(cy1 * Ww + cx0) * 64;
    size_t o11 = (size_t)(cy1 * Ww + cx1) * 64;
    t.w00 = (1.f - ly) * (1.f - lx) * (fy0 * fx0);
    t.w01 = (1.f - ly) * lx * (fy0 * fx1);
    t.w10 = ly * (1.f - lx) * (fy1 * fx0);
    t.w11 = ly * lx * (fy1 * fx1);
    const ushort* pa = xb + chof;
    t.c00 = *(const uint4*)(pa + o00);
    t.c01 = *(const uint4*)(pa + o01);
    t.c10 = *(const uint4*)(pa + o10);
    t.c11 = *(const uint4*)(pa + o11);
  };

  TapG tA, tB;
  tap_issue(0, tA);

  #pragma unroll
  for (int k = 0; k < 9; ++k) {
    TapG& cur = (k & 1) ? tB : tA;
    TapG& nxt = (k & 1) ? tA : tB;
    if (k < 8) tap_issue(k + 1, nxt);   // gathers in flight during interp

    // B-fragments (L1-resident after first use)
    const ushort* wk = wtb + (size_t)k * 4096 + chof;
    uint4 bfr[4];
    #pragma unroll
    for (int nt = 0; nt < 4; ++nt)
      bfr[nt] = *(const uint4*)(wk + (nt * 16 + m) * 64);

    // interpolate pairwise, repack to bf16
    uint ua[4];
    {
      const uint* pc00 = (const uint*)&cur.c00;
      const uint* pc01 = (const uint*)&cur.c01;
      const uint* pc10 = (const uint*)&cur.c10;
      const uint* pc11 = (const uint*)&cur.c11;
      #pragma unroll
      for (int q = 0; q < 4; ++q) {
        float vlo = fmaf(cur.w11, bflo(pc11[q]), fmaf(cur.w10, bflo(pc10[q]),
                    fmaf(cur.w01, bflo(pc01[q]), cur.w00 * bflo(pc00[q]))));
        float vhi = fmaf(cur.w11, bfhi(pc11[q]), fmaf(cur.w10, bfhi(pc10[q]),
                    fmaf(cur.w01, bfhi(pc01[q]), cur.w00 * bfhi(pc00[q]))));
        ua[q] = pack_rne(vlo, vhi);
      }
    }
    bf16x8 a0;
    __builtin_memcpy(&a0, ua, 16);

    #pragma unroll
    for (int nt = 0; nt < 4; ++nt) {
      bf16x8 b0;
      __builtin_memcpy(&b0, &bfr[nt], 16);
      acc[nt] = __builtin_amdgcn_mfma_f32_16x16x32_bf16(a0, b0, acc[nt], 0, 0, 0);
    }
  }

  // ---------------- epilogue: combine kh halves, transpose, store + BN -----
  // step 1: high waves deposit partials into P view = lds_f[pg][o][17]
  if (kh == 1) {
    #pragma unroll
    for (int nt = 0; nt < 4; ++nt)
      #pragma unroll
      for (int r = 0; r < 4; ++r)
        lds_f[pg * 1088 + (nt * 16 + m) * 17 + hi * 4 + r] = acc[nt][r];
  }
  __syncthreads();
  // step 2: low waves read partner partials into registers
  if (kh == 0) {
    #pragma unroll
    for (int nt = 0; nt < 4; ++nt)
      #pragma unroll
      for (int r = 0; r < 4; ++r)
        acc[nt][r] += lds_f[pg * 1088 + (nt * 16 + m) * 17 + hi * 4 + r];
  }
  __syncthreads();
  // step 3: low waves write transpose view T[o][68]
  if (kh == 0) {
    #pragma unroll
    for (int nt = 0; nt < 4; ++nt) {
      float bo = b_def[nt * 16 + m];
      float4 v;
      v.x = acc[nt][0] + bo;
      v.y = acc[nt][1] + bo;
      v.z = acc[nt][2] + bo;
      v.w = acc[nt][3] + bo;
      *(float4*)&lds_f[(nt * 16 + m) * 68 + pg * 16 + hi * 4] = v;
    }
  }
  __syncthreads();
  // step 4: first 256 threads do coalesced stores + BN partial sums
  if (tid < 256) {
    int o = tid >> 2, part = tid & 3;
    const float* rb = lds_f + o * 68 + part * 16;
    float* op = out + ((size_t)(b * 64 + o)) * HW + pbase + part * 16;
    float s = 0.f, ss = 0.f;
    #pragma unroll
    for (int j = 0; j < 4; ++j) {
      float4 v = *(const float4*)&rb[4 * j];
      s += v.x + v.y + v.z + v.w;
      ss += v.x * v.x + v.y * v.y + v.z * v.z + v.w * v.w;
      *(float4*)&op[4 * j] = v;
    }
    red[tid] = s;
    red[256 + tid] = ss;
  }
  __syncthreads();
  if (tid < 64) {
    float rs = red[4 * tid] + red[4 * tid + 1] + red[4 * tid + 2] + red[4 * tid + 3];
    float rq = red[256 + 4 * tid] + red[256 + 4 * tid + 1] +
               red[256 + 4 * tid + 2] + red[256 + 4 * tid + 3];
    parts[(size_t)tid * 1152 + blk] = rs;
    parts[73728 + (size_t)tid * 1152 + blk] = rq;
  }
}

// ---------------------------------------------------------------------------
// K3: finalize BN scale/shift.  64 blocks x 256 threads.
// ---------------------------------------------------------------------------
__global__ __launch_bounds__(256) void k_stats(
    const float* __restrict__ parts, const float* __restrict__ gamma,
    const float* __restrict__ beta, float* __restrict__ stats)
{
  int c = blockIdx.x;
  int tid = threadIdx.x;
  float s = 0.f, ss = 0.f;
  for (int i = tid; i < 1152; i += 256) {
    s += parts[(size_t)c * 1152 + i];
    ss += parts[73728 + (size_t)c * 1152 + i];
  }
  #pragma unroll
  for (int off = 32; off >= 1; off >>= 1) {
    s += __shfl_down(s, off);
    ss += __shfl_down(ss, off);
  }
  __shared__ float rs[4], rss[4];
  int wave = tid >> 6, lane = tid & 63;
  if (lane == 0) { rs[wave] = s; rss[wave] = ss; }
  __syncthreads();
  if (tid == 0) {
    float S1 = rs[0] + rs[1] + rs[2] + rs[3];
    float S2 = rss[0] + rss[1] + rss[2] + rss[3];
    const float inv = 1.f / 73728.f;
    float mean = S1 * inv;
    float var = S2 * inv - mean * mean;
    float scale = gamma[c] * rsqrtf(var + 1e-5f);
    stats[c] = scale;
    stats[64 + c] = beta[c] - mean * scale;
  }
}

// ---------------------------------------------------------------------------
// K4: in-place normalize + affine + relu, float4 vectorized.
// ---------------------------------------------------------------------------
__global__ __launch_bounds__(256) void k_norm(
    float* __restrict__ out, const float* __restrict__ stats)
{
  int g = blockIdx.x * 256 + threadIdx.x;   // over 1179648 float4
  int o = (g / 2304) & 63;                  // 2304 float4 per plane
  float sc = stats[o], sh = stats[64 + o];
  float4 v = ((const float4*)out)[g];
  v.x = fmaxf(fmaf(v.x, sc, sh), 0.f);
  v.y = fmaxf(fmaf(v.y, sc, sh), 0.f);
  v.z = fmaxf(fmaf(v.z, sc, sh), 0.f);
  v.w = fmaxf(fmaf(v.w, sc, sh), 0.f);
  ((float4*)out)[g] = v;
}

extern "C" void kernel_launch(void* const* d_in, const int* in_sizes, int n_in,
                              void* d_out, int out_size, void* d_ws, size_t ws_size,
                              hipStream_t stream) {
  const float* x     = (const float*)d_in[0];
  const float* w_off = (const float*)d_in[1];
  const float* b_off = (const float*)d_in[2];
  const float* w_def = (const float*)d_in[3];
  const float* b_def = (const float*)d_in[4];
  const float* gamma = (const float*)d_in[5];
  const float* beta  = (const float*)d_in[6];
  float* out = (float*)d_out;

  // workspace layout (float slots): wtb | wob | xt | parts | stats
  float* base  = (float*)d_ws;
  ushort* wtb  = (ushort*)base;                    // 36864 bf16 (18432 slots)
  ushort* wob  = (ushort*)(base + 18432);          // 18432 bf16 (9216 slots)
  ushort* xt   = (ushort*)(base + 18432 + 9216);   // 4718592 bf16 (2359296 slots)
  float* parts = base + 18432 + 9216 + 2359296;    // 147456
  float* stats = parts + 147456;                   // 128

  k_xt<<<1152, 256, 0, stream>>>(x, w_def, w_off, xt, wtb, wob);
  k_deform<<<1152, 512, 0, stream>>>(xt, wtb, wob, b_off, b_def, out, parts);
  k_stats<<<64, 256, 0, stream>>>(parts, gamma, beta, stats);
  k_norm<<<4608, 256, 0, stream>>>(out, stats);
}

// Round 7
// 66.945 us; speedup vs baseline: 2.0294x; 2.0294x over previous
//
#include <hip/hip_runtime.h>

#define Hh 96
#define Ww 96
#define CIN 64
#define COUT 64
#define BATCH 8
#define HW 9216           // Hh*Ww
#define NOFF 18           // 2*K*K

// LDS layout (bytes) for k_main
#define XS_ROW   13824            // 96 px * 144B (128B data + 16B pad)
#define XS_SIZE  124416           // 9 rows
#define WS_BASE  124416           // wob [9][18][144]=23328 ; later wtb dbuf [2][64*144=9216]
#define OF_BASE  147744           // offs [288 px][20 j] bf16 = 11520
#define SM_TOTAL 159264

typedef __attribute__((ext_vector_type(8))) short bf16x8;
typedef __attribute__((ext_vector_type(4))) float f32x4;

__device__ inline ushort f2bf(float f) {
  union { float f; uint u; } v; v.f = f;
  uint u = v.u;
  u += 0x7FFF + ((u >> 16) & 1);     // RNE
  return (ushort)(u >> 16);
}
__device__ inline float bf2f(ushort s) {
  union { uint u; float f; } v; v.u = ((uint)s) << 16; return v.f;
}
__device__ inline float bflo(uint u) {
  union { uint u; float f; } v; v.u = u << 16; return v.f;
}
__device__ inline float bfhi(uint u) {
  union { uint u; float f; } v; v.u = u & 0xFFFF0000u; return v.f;
}
__device__ inline uint pack_rne(float a, float b) {
  union { float f; uint u; } x, y; x.f = a; y.f = b;
  uint ua = x.u + (0x7FFFu + ((x.u >> 16) & 1));
  uint ub = y.u + (0x7FFFu + ((y.u >> 16) & 1));
  return (ua >> 16) | (ub & 0xFFFF0000u);
}
__device__ inline uint interp_pack(uint p00, uint p01, uint p10, uint p11,
                                   float w00, float w01, float w10, float w11) {
  float vlo = fmaf(w11, bflo(p11), fmaf(w10, bflo(p10),
              fmaf(w01, bflo(p01), w00 * bflo(p00))));
  float vhi = fmaf(w11, bfhi(p11), fmaf(w10, bfhi(p10),
              fmaf(w01, bfhi(p01), w00 * bfhi(p00))));
  return pack_rne(vlo, vhi);
}

// ---------------------------------------------------------------------------
// K0: transpose x (NCHW f32) -> xt (NHWC bf16) via padded LDS tile, + pack
// weights (wtb [k][o][c], wob [k][n<32][c]) in low blocks.
// ---------------------------------------------------------------------------
__global__ __launch_bounds__(256) void k_xt(
    const float* __restrict__ x, const float* __restrict__ w_def,
    const float* __restrict__ w_off, ushort* __restrict__ xt,
    ushort* __restrict__ wtb, ushort* __restrict__ wob)
{
  __shared__ float tile[64][65];
  int tid = threadIdx.x;
  int blk = blockIdx.x;

  if (blk < 9) {            // wtb[k][o][c] = bf16(w_def[o][c][k]), k = blk
    for (int i = tid; i < 4096; i += 256) {
      int o = i >> 6, c = i & 63;
      wtb[blk * 4096 + i] = f2bf(w_def[(o * 64 + c) * 9 + blk]);
    }
  } else if (blk < 25 && blk >= 16) {   // wob[k][n(32)][c], k = blk-16
    int k = blk - 16;
    for (int i = tid; i < 2048; i += 256) {
      int n = i >> 6, c = i & 63;
      wob[k * 2048 + i] = (n < NOFF) ? f2bf(w_off[(n * 64 + c) * 9 + k]) : (ushort)0;
    }
  }

  int b = blk / 144;
  int pbase = (blk - b * 144) * 64;
  int wave = tid >> 6, lane = tid & 63;
  const float* xp = x + (size_t)b * CIN * HW + pbase;
  #pragma unroll
  for (int i = 0; i < 16; ++i) {
    int c = wave * 16 + i;
    tile[lane][c] = xp[(size_t)c * HW + lane];
  }
  __syncthreads();
  ushort* xo = xt + ((size_t)b * HW + pbase) * 64;
  #pragma unroll
  for (int i = 0; i < 16; ++i) {
    int p = wave * 16 + i;
    xo[(size_t)p * 64 + lane] = f2bf(tile[p][lane]);
  }
}

// ---------------------------------------------------------------------------
// K1: fully-fused LDS-resident tile kernel.
// 256 blocks = 8 batches (XCD) x 32 row-triples.  512 threads (8 waves).
// Stage 9 halo rows of NHWC bf16 x into LDS (144B stride), then:
//   Phase A: offset conv via MFMA (kh-split waves), exchange via LDS.
//   Phase B: 4-corner bilinear gathers as ds_read_b128 + MFMA; w_def tap
//            double-buffered 8KB staging per k.
//   Epilogue: LDS transpose (alias x region), coalesced f32 stores + BN sums.
// Task map: 36 tasks = 18 px-groups x 2 kh; wave w owns kh=w&1,
// groups (w>>1)+4*ti, ti<5 while g<18.
// ---------------------------------------------------------------------------
__global__ __launch_bounds__(512, 2) void k_main(
    const ushort* __restrict__ xt, const ushort* __restrict__ wtb,
    const ushort* __restrict__ wob, const float* __restrict__ b_off,
    const float* __restrict__ b_def, float* __restrict__ out,
    float* __restrict__ parts)
{
  extern __shared__ char sm[];
  int tid = threadIdx.x;
  int bid = blockIdx.x;
  int b = bid & 7;                 // batch = XCD
  int rt = bid >> 3;
  int r0 = rt * 3;

  // ---- stage xs: rows clamp(r0-3+s) for s in [0,9) ----
  {
    const ushort* xsrc = xt + (size_t)b * HW * 64;
    for (int q = tid; q < 6912; q += 512) {
      int s = q / 768;
      int rem = q - s * 768;
      int cxp = rem >> 3, c16 = rem & 7;
      int srow = min(max(r0 - 3 + s, 0), 95);
      uint4 v = *(const uint4*)(xsrc + (size_t)(srow * 96 + cxp) * 64 + c16 * 8);
      *(uint4*)(sm + s * XS_ROW + cxp * 144 + c16 * 16) = v;
    }
  }
  // ---- stage wob: [9][18][144] ----
  for (int q = tid; q < 1296; q += 512) {
    int k = q / 144;
    int rem = q - k * 144;
    int n = rem >> 3, c16 = rem & 7;
    uint4 v = *(const uint4*)(wob + k * 2048 + n * 64 + c16 * 8);
    *(uint4*)(sm + WS_BASE + k * 2592 + n * 144 + c16 * 16) = v;
  }
  __syncthreads();

  int wave = tid >> 6, lane = tid & 63;
  int m = lane & 15, hi = lane >> 4;
  int kh = wave & 1;
  int gb = wave >> 1;
  int khB = kh * 64, hiB = hi * 16;

  // per-task geometry
  int hA[5], wAc[5], pPix[5], gV[5];
  #pragma unroll
  for (int ti = 0; ti < 5; ++ti) {
    int g = gb + ti * 4;
    gV[ti] = g;
    int gr = g / 6, gc = g - gr * 6;
    hA[ti] = r0 + gr;
    wAc[ti] = gc * 16 + m;
    pPix[ti] = g * 16 + m;
  }

  // ---------------- Phase A: offset conv (K=32 per wave) -------------------
  f32x4 oacc[5][2];
  #pragma unroll
  for (int ti = 0; ti < 5; ++ti) {
    oacc[ti][0] = (f32x4){0.f, 0.f, 0.f, 0.f};
    oacc[ti][1] = (f32x4){0.f, 0.f, 0.f, 0.f};
  }
  for (int k = 0; k < 9; ++k) {
    int ky = k / 3 - 1, kx = (k - (k / 3) * 3) - 1;
    const char* wkb = sm + WS_BASE + k * 2592;
    bf16x8 wb0 = *(const bf16x8*)(wkb + m * 144 + hiB + khB);
    int r1 = min(16 + m, 17);
    bf16x8 wb1 = *(const bf16x8*)(wkb + r1 * 144 + hiB + khB);
    #pragma unroll
    for (int ti = 0; ti < 5; ++ti) {
      if (gV[ti] < 18) {
        int yy = hA[ti] + ky, xx = wAc[ti] + kx;
        bool valid = (yy >= 0 && yy < Hh && xx >= 0 && xx < Ww);
        int cy = min(max(yy, 0), 95), cx = min(max(xx, 0), 95);
        int sy = cy - r0 + 3;
        bf16x8 a = *(const bf16x8*)(sm + sy * XS_ROW + cx * 144 + hiB + khB);
        if (!valid) a = (bf16x8)0;
        oacc[ti][0] = __builtin_amdgcn_mfma_f32_16x16x32_bf16(a, wb0, oacc[ti][0], 0, 0, 0);
        oacc[ti][1] = __builtin_amdgcn_mfma_f32_16x16x32_bf16(a, wb1, oacc[ti][1], 0, 0, 0);
      }
    }
  }

  // offsets exchange via OF region: [pix][20 j] bf16
  int j0 = m, j1 = 16 + m;
  if (kh == 1) {
    #pragma unroll
    for (int ti = 0; ti < 5; ++ti) {
      if (gV[ti] < 18) {
        #pragma unroll
        for (int r = 0; r < 4; ++r) {
          int p = gV[ti] * 16 + hi * 4 + r;
          *(ushort*)(sm + OF_BASE + p * 40 + j0 * 2) = f2bf(oacc[ti][0][r]);
          if (m < 2)
            *(ushort*)(sm + OF_BASE + p * 40 + j1 * 2) = f2bf(oacc[ti][1][r]);
        }
      }
    }
  }
  __syncthreads();
  if (kh == 0) {
    float bo0 = b_off[j0];
    float bo1 = (m < 2) ? b_off[j1] : 0.f;
    #pragma unroll
    for (int ti = 0; ti < 5; ++ti) {
      if (gV[ti] < 18) {
        #pragma unroll
        for (int r = 0; r < 4; ++r) {
          int p = gV[ti] * 16 + hi * 4 + r;
          ushort* a0p = (ushort*)(sm + OF_BASE + p * 40 + j0 * 2);
          *a0p = f2bf(oacc[ti][0][r] + bf2f(*a0p) + bo0);
          if (m < 2) {
            ushort* a1p = (ushort*)(sm + OF_BASE + p * 40 + j1 * 2);
            *a1p = f2bf(oacc[ti][1][r] + bf2f(*a1p) + bo1);
          }
        }
      }
    }
  }
  // stage wtb k=0 into dbuf slot 0 (overwrites wob region; phase A done)
  {
    int o = tid >> 3, c16 = tid & 7;
    uint4 v = *(const uint4*)(wtb + o * 64 + c16 * 8);
    *(uint4*)(sm + WS_BASE + o * 144 + c16 * 16) = v;
  }
  __syncthreads();

  // ---------------- Phase B: deform loop from LDS --------------------------
  f32x4 acc[5][4];
  #pragma unroll
  for (int ti = 0; ti < 5; ++ti)
    #pragma unroll
    for (int nt = 0; nt < 4; ++nt) acc[ti][nt] = (f32x4){0.f, 0.f, 0.f, 0.f};

  for (int k = 0; k < 9; ++k) {
    if (k < 8) {    // prefetch next tap's w_def into other dbuf slot
      int o = tid >> 3, c16 = tid & 7;
      uint4 v = *(const uint4*)(wtb + (k + 1) * 4096 + o * 64 + c16 * 8);
      *(uint4*)(sm + WS_BASE + ((k + 1) & 1) * 9216 + o * 144 + c16 * 16) = v;
    }
    int ky = k / 3 - 1, kx = (k - (k / 3) * 3) - 1;
    const char* wkb = sm + WS_BASE + (k & 1) * 9216;
    bf16x8 bf0 = *(const bf16x8*)(wkb + m * 144 + hiB + khB);
    bf16x8 bf1 = *(const bf16x8*)(wkb + (16 + m) * 144 + hiB + khB);
    bf16x8 bf2 = *(const bf16x8*)(wkb + (32 + m) * 144 + hiB + khB);
    bf16x8 bf3 = *(const bf16x8*)(wkb + (48 + m) * 144 + hiB + khB);

    #pragma unroll
    for (int ti = 0; ti < 5; ++ti) {
      if (gV[ti] < 18) {
        uint dd = *(const uint*)(sm + OF_BASE + pPix[ti] * 40 + k * 4);
        float dy = bflo(dd), dx = bfhi(dd);
        float py = (float)(hA[ti] + ky) + dy;
        float px = (float)(wAc[ti] + kx) + dx;
        float y0f = floorf(py), x0f = floorf(px);
        float ly = py - y0f, lx = px - x0f;
        int y0 = (int)y0f, x0 = (int)x0f;
        int y1 = y0 + 1, x1 = x0 + 1;
        float fy0 = (y0 >= 0 && y0 < Hh) ? 1.f : 0.f;
        float fy1 = (y1 >= 0 && y1 < Hh) ? 1.f : 0.f;
        float fx0 = (x0 >= 0 && x0 < Ww) ? 1.f : 0.f;
        float fx1 = (x1 >= 0 && x1 < Ww) ? 1.f : 0.f;
        int cy0 = min(max(y0, 0), 95), cy1 = min(max(y1, 0), 95);
        int cx0 = min(max(x0, 0), 95), cx1 = min(max(x1, 0), 95);
        int sy0 = min(max(cy0 - r0 + 3, 0), 8);
        int sy1 = min(max(cy1 - r0 + 3, 0), 8);
        const char* row0 = sm + sy0 * XS_ROW;
        const char* row1 = sm + sy1 * XS_ROW;
        uint4 c00 = *(const uint4*)(row0 + cx0 * 144 + hiB + khB);
        uint4 c01 = *(const uint4*)(row0 + cx1 * 144 + hiB + khB);
        uint4 c10 = *(const uint4*)(row1 + cx0 * 144 + hiB + khB);
        uint4 c11 = *(const uint4*)(row1 + cx1 * 144 + hiB + khB);
        float w00 = (1.f - ly) * (1.f - lx) * (fy0 * fx0);
        float w01 = (1.f - ly) * lx * (fy0 * fx1);
        float w10 = ly * (1.f - lx) * (fy1 * fx0);
        float w11 = ly * lx * (fy1 * fx1);
        uint ua[4];
        ua[0] = interp_pack(c00.x, c01.x, c10.x, c11.x, w00, w01, w10, w11);
        ua[1] = interp_pack(c00.y, c01.y, c10.y, c11.y, w00, w01, w10, w11);
        ua[2] = interp_pack(c00.z, c01.z, c10.z, c11.z, w00, w01, w10, w11);
        ua[3] = interp_pack(c00.w, c01.w, c10.w, c11.w, w00, w01, w10, w11);
        bf16x8 av;
        __builtin_memcpy(&av, ua, 16);
        acc[ti][0] = __builtin_amdgcn_mfma_f32_16x16x32_bf16(av, bf0, acc[ti][0], 0, 0, 0);
        acc[ti][1] = __builtin_amdgcn_mfma_f32_16x16x32_bf16(av, bf1, acc[ti][1], 0, 0, 0);
        acc[ti][2] = __builtin_amdgcn_mfma_f32_16x16x32_bf16(av, bf2, acc[ti][2], 0, 0, 0);
        acc[ti][3] = __builtin_amdgcn_mfma_f32_16x16x32_bf16(av, bf3, acc[ti][3], 0, 0, 0);
      }
    }
    __syncthreads();
  }

  // ---------------- epilogue: transpose via LDS (alias xs), store + BN -----
  float* T = (float*)sm;     // [64][289] f32
  {
    float bd[4];
    bd[0] = b_def[m]; bd[1] = b_def[16 + m];
    bd[2] = b_def[32 + m]; bd[3] = b_def[48 + m];
    #pragma unroll
    for (int ti = 0; ti < 5; ++ti) {
      if (gV[ti] < 18) {
        #pragma unroll
        for (int nt = 0; nt < 4; ++nt) {
          int o = nt * 16 + m;
          #pragma unroll
          for (int r = 0; r < 4; ++r) {
            int p = gV[ti] * 16 + hi * 4 + r;
            // kh halves both write their partial? no: need sum of kh0+kh1.
            // kh1 writes first, kh0 adds after barrier (below).
            if (kh == 1) T[o * 289 + p] = acc[ti][nt][r];
          }
        }
      }
    }
  }
  __syncthreads();
  if (kh == 0) {
    float bd[4];
    bd[0] = b_def[m]; bd[1] = b_def[16 + m];
    bd[2] = b_def[32 + m]; bd[3] = b_def[48 + m];
    #pragma unroll
    for (int ti = 0; ti < 5; ++ti) {
      if (gV[ti] < 18) {
        #pragma unroll
        for (int nt = 0; nt < 4; ++nt) {
          int o = nt * 16 + m;
          #pragma unroll
          for (int r = 0; r < 4; ++r) {
            int p = gV[ti] * 16 + hi * 4 + r;
            T[o * 289 + p] += acc[ti][nt][r] + bd[nt];
          }
        }
      }
    }
  }
  __syncthreads();
  {
    int o = tid >> 3, seg = tid & 7;
    const float* Tr = T + o * 289 + seg * 36;
    float* og = out + ((size_t)(b * 64 + o)) * HW + rt * 288 + seg * 36;
    float s = 0.f, ss = 0.f;
    #pragma unroll
    for (int j4 = 0; j4 < 9; ++j4) {
      float4 v;
      v.x = Tr[j4 * 4 + 0]; v.y = Tr[j4 * 4 + 1];
      v.z = Tr[j4 * 4 + 2]; v.w = Tr[j4 * 4 + 3];
      s += v.x + v.y + v.z + v.w;
      ss += v.x * v.x + v.y * v.y + v.z * v.z + v.w * v.w;
      *(float4*)(og + j4 * 4) = v;
    }
    s += __shfl_down(s, 4); s += __shfl_down(s, 2); s += __shfl_down(s, 1);
    ss += __shfl_down(ss, 4); ss += __shfl_down(ss, 2); ss += __shfl_down(ss, 1);
    if ((tid & 7) == 0) {
      parts[o * 256 + bid] = s;
      parts[16384 + o * 256 + bid] = ss;
    }
  }
}

// ---------------------------------------------------------------------------
// K3: finalize BN scale/shift.  64 blocks x 256 threads.
// ---------------------------------------------------------------------------
__global__ __launch_bounds__(256) void k_stats(
    const float* __restrict__ parts, const float* __restrict__ gamma,
    const float* __restrict__ beta, float* __restrict__ stats)
{
  int c = blockIdx.x;
  int tid = threadIdx.x;
  float s = 0.f, ss = 0.f;
  for (int i = tid; i < 256; i += 256) {
    s += parts[c * 256 + i];
    ss += parts[16384 + c * 256 + i];
  }
  #pragma unroll
  for (int off = 32; off >= 1; off >>= 1) {
    s += __shfl_down(s, off);
    ss += __shfl_down(ss, off);
  }
  __shared__ float rs[4], rss[4];
  int wave = tid >> 6, lane = tid & 63;
  if (lane == 0) { rs[wave] = s; rss[wave] = ss; }
  __syncthreads();
  if (tid == 0) {
    float S1 = rs[0] + rs[1] + rs[2] + rs[3];
    float S2 = rss[0] + rss[1] + rss[2] + rss[3];
    const float inv = 1.f / 73728.f;
    float mean = S1 * inv;
    float var = S2 * inv - mean * mean;
    float scale = gamma[c] * rsqrtf(var + 1e-5f);
    stats[c] = scale;
    stats[64 + c] = beta[c] - mean * scale;
  }
}

// ---------------------------------------------------------------------------
// K4: in-place normalize + affine + relu, float4 vectorized.
// ---------------------------------------------------------------------------
__global__ __launch_bounds__(256) void k_norm(
    float* __restrict__ out, const float* __restrict__ stats)
{
  int g = blockIdx.x * 256 + threadIdx.x;
  int o = (g / 2304) & 63;
  float sc = stats[o], sh = stats[64 + o];
  float4 v = ((const float4*)out)[g];
  v.x = fmaxf(fmaf(v.x, sc, sh), 0.f);
  v.y = fmaxf(fmaf(v.y, sc, sh), 0.f);
  v.z = fmaxf(fmaf(v.z, sc, sh), 0.f);
  v.w = fmaxf(fmaf(v.w, sc, sh), 0.f);
  ((float4*)out)[g] = v;
}

extern "C" void kernel_launch(void* const* d_in, const int* in_sizes, int n_in,
                              void* d_out, int out_size, void* d_ws, size_t ws_size,
                              hipStream_t stream) {
  const float* x     = (const float*)d_in[0];
  const float* w_off = (const float*)d_in[1];
  const float* b_off = (const float*)d_in[2];
  const float* w_def = (const float*)d_in[3];
  const float* b_def = (const float*)d_in[4];
  const float* gamma = (const float*)d_in[5];
  const float* beta  = (const float*)d_in[6];
  float* out = (float*)d_out;

  // workspace layout (float slots): wtb | wob | xt | parts | stats
  float* base  = (float*)d_ws;
  ushort* wtb  = (ushort*)base;                    // 36864 bf16 (18432 slots)
  ushort* wob  = (ushort*)(base + 18432);          // 18432 bf16 (9216 slots)
  ushort* xt   = (ushort*)(base + 18432 + 9216);   // 4718592 bf16 (2359296 slots)
  float* parts = base + 18432 + 9216 + 2359296;    // 32768
  float* stats = parts + 32768;                    // 128

  static bool attr_set = false;
  (void)hipFuncSetAttribute((const void*)k_main,
      hipFuncAttributeMaxDynamicSharedMemorySize, SM_TOTAL);

  k_xt<<<1152, 256, 0, stream>>>(x, w_def, w_off, xt, wtb, wob);
  k_main<<<256, 512, SM_TOTAL, stream>>>(xt, wtb, wob, b_off, b_def, out, parts);
  k_stats<<<64, 256, 0, stream>>>(parts, gamma, beta, stats);
  k_norm<<<4608, 256, 0, stream>>>(out, stats);
}

// Round 8
// 59.886 us; speedup vs baseline: 2.2687x; 1.1179x over previous
//
#include <hip/hip_runtime.h>

#define Hh 96
#define Ww 96
#define CIN 64
#define COUT 64
#define BATCH 8
#define HW 9216           // Hh*Ww
#define NOFF 18           // 2*K*K

// LDS layout (bytes) for k_main
#define XS_ROW   13824            // 96 px * 144B (128B data + 16B pad)
#define XS_SIZE  124416           // 9 rows
#define WS_BASE  124416           // wob [9][18][144]=23328 ; later wtb dbuf [2][9216]
#define OF_BASE  147744           // offs [288 px][20 j] bf16 = 11520
#define SM_TOTAL 159264

typedef __attribute__((ext_vector_type(8))) short bf16x8;
typedef __attribute__((ext_vector_type(4))) float f32x4;

__device__ inline ushort f2bf(float f) {
  union { float f; uint u; } v; v.f = f;
  uint u = v.u;
  u += 0x7FFF + ((u >> 16) & 1);     // RNE
  return (ushort)(u >> 16);
}
__device__ inline float bf2f(ushort s) {
  union { uint u; float f; } v; v.u = ((uint)s) << 16; return v.f;
}
__device__ inline float bflo(uint u) {
  union { uint u; float f; } v; v.u = u << 16; return v.f;
}
__device__ inline float bfhi(uint u) {
  union { uint u; float f; } v; v.u = u & 0xFFFF0000u; return v.f;
}
__device__ inline uint cvtpk(float lo, float hi) {   // {bf(lo), bf(hi)} in 1 instr
  uint r;
  asm("v_cvt_pk_bf16_f32 %0, %1, %2" : "=v"(r) : "v"(lo), "v"(hi));
  return r;
}
__device__ inline uint interp_pack(uint p00, uint p01, uint p10, uint p11,
                                   float w00, float w01, float w10, float w11) {
  float vlo = fmaf(w11, bflo(p11), fmaf(w10, bflo(p10),
              fmaf(w01, bflo(p01), w00 * bflo(p00))));
  float vhi = fmaf(w11, bfhi(p11), fmaf(w10, bfhi(p10),
              fmaf(w01, bfhi(p01), w00 * bfhi(p00))));
  return cvtpk(vlo, vhi);
}

// ---------------------------------------------------------------------------
// K0: transpose x (NCHW f32) -> xt (NHWC bf16) via padded LDS tile, + pack
// weights (wtb [k][o][c], wob [k][n<32][c]) in low blocks.
// ---------------------------------------------------------------------------
__global__ __launch_bounds__(256) void k_xt(
    const float* __restrict__ x, const float* __restrict__ w_def,
    const float* __restrict__ w_off, ushort* __restrict__ xt,
    ushort* __restrict__ wtb, ushort* __restrict__ wob)
{
  __shared__ float tile[64][65];
  int tid = threadIdx.x;
  int blk = blockIdx.x;

  if (blk < 9) {            // wtb[k][o][c] = bf16(w_def[o][c][k]), k = blk
    for (int i = tid; i < 4096; i += 256) {
      int o = i >> 6, c = i & 63;
      wtb[blk * 4096 + i] = f2bf(w_def[(o * 64 + c) * 9 + blk]);
    }
  } else if (blk < 25 && blk >= 16) {   // wob[k][n(32)][c], k = blk-16
    int k = blk - 16;
    for (int i = tid; i < 2048; i += 256) {
      int n = i >> 6, c = i & 63;
      wob[k * 2048 + i] = (n < NOFF) ? f2bf(w_off[(n * 64 + c) * 9 + k]) : (ushort)0;
    }
  }

  int b = blk / 144;
  int pbase = (blk - b * 144) * 64;
  int wave = tid >> 6, lane = tid & 63;
  const float* xp = x + (size_t)b * CIN * HW + pbase;
  #pragma unroll
  for (int i = 0; i < 16; ++i) {
    int c = wave * 16 + i;
    tile[lane][c] = xp[(size_t)c * HW + lane];
  }
  __syncthreads();
  ushort* xo = xt + ((size_t)b * HW + pbase) * 64;
  #pragma unroll
  for (int i = 0; i < 16; ++i) {
    int p = wave * 16 + i;
    xo[(size_t)p * 64 + lane] = f2bf(tile[p][lane]);
  }
}

// ---------------------------------------------------------------------------
// K1: fully-fused LDS-resident tile kernel.
// 256 blocks = 8 batches (XCD) x 32 row-triples.  768 threads (12 waves).
// Task map: 36 tasks = 18 px-groups x 2 kh; wave w: kh=w&1, gb=w>>1 (0..5),
// groups g = gb + 6*ti, ti<3  -> EXACTLY 3 tasks per wave (perfect balance).
// ---------------------------------------------------------------------------
__global__ __launch_bounds__(768, 3) void k_main(
    const ushort* __restrict__ xt, const ushort* __restrict__ wtb,
    const ushort* __restrict__ wob, const float* __restrict__ b_off,
    const float* __restrict__ b_def, float* __restrict__ out,
    float* __restrict__ parts)
{
  extern __shared__ char sm[];
  int tid = threadIdx.x;
  int bid = blockIdx.x;
  int b = bid & 7;                 // batch = XCD
  int rt = bid >> 3;
  int r0 = rt * 3;

  // ---- stage xs: rows clamp(r0-3+s) for s in [0,9) ----
  {
    const ushort* xsrc = xt + (size_t)b * HW * 64;
    for (int q = tid; q < 6912; q += 768) {
      int s = q / 768;
      int rem = q - s * 768;
      int cxp = rem >> 3, c16 = rem & 7;
      int srow = min(max(r0 - 3 + s, 0), 95);
      uint4 v = *(const uint4*)(xsrc + (size_t)(srow * 96 + cxp) * 64 + c16 * 8);
      *(uint4*)(sm + s * XS_ROW + cxp * 144 + c16 * 16) = v;
    }
  }
  // ---- stage wob: [9][18][144] ----
  for (int q = tid; q < 1296; q += 768) {
    int k = q / 144;
    int rem = q - k * 144;
    int n = rem >> 3, c16 = rem & 7;
    uint4 v = *(const uint4*)(wob + k * 2048 + n * 64 + c16 * 8);
    *(uint4*)(sm + WS_BASE + k * 2592 + n * 144 + c16 * 16) = v;
  }
  __syncthreads();

  int wave = tid >> 6, lane = tid & 63;
  int m = lane & 15, hi = lane >> 4;
  int kh = wave & 1;
  int gb = wave >> 1;                       // 0..5
  int khB = kh * 64, hiB = hi * 16;

  // per-task geometry (all valid: g = gb + 6*ti < 18)
  int hA[3], wAc[3], pPix[3], gV[3];
  #pragma unroll
  for (int ti = 0; ti < 3; ++ti) {
    int g = gb + ti * 6;
    gV[ti] = g;
    int gr = g / 6, gc = g - gr * 6;
    hA[ti] = r0 + gr;
    wAc[ti] = gc * 16 + m;
    pPix[ti] = g * 16 + m;
  }

  // ---------------- Phase A: offset conv (K=32 per wave) -------------------
  f32x4 oacc[3][2];
  #pragma unroll
  for (int ti = 0; ti < 3; ++ti) {
    oacc[ti][0] = (f32x4){0.f, 0.f, 0.f, 0.f};
    oacc[ti][1] = (f32x4){0.f, 0.f, 0.f, 0.f};
  }
  for (int k = 0; k < 9; ++k) {
    int ky = k / 3 - 1, kx = (k - (k / 3) * 3) - 1;
    const char* wkb = sm + WS_BASE + k * 2592;
    bf16x8 wb0 = *(const bf16x8*)(wkb + m * 144 + hiB + khB);
    int r1 = min(16 + m, 17);
    bf16x8 wb1 = *(const bf16x8*)(wkb + r1 * 144 + hiB + khB);
    #pragma unroll
    for (int ti = 0; ti < 3; ++ti) {
      int yy = hA[ti] + ky, xx = wAc[ti] + kx;
      bool valid = (yy >= 0 && yy < Hh && xx >= 0 && xx < Ww);
      int cy = min(max(yy, 0), 95), cx = min(max(xx, 0), 95);
      int sy = cy - r0 + 3;
      bf16x8 a = *(const bf16x8*)(sm + sy * XS_ROW + cx * 144 + hiB + khB);
      if (!valid) a = (bf16x8)0;
      oacc[ti][0] = __builtin_amdgcn_mfma_f32_16x16x32_bf16(a, wb0, oacc[ti][0], 0, 0, 0);
      oacc[ti][1] = __builtin_amdgcn_mfma_f32_16x16x32_bf16(a, wb1, oacc[ti][1], 0, 0, 0);
    }
  }

  // offsets exchange via OF region: [pix][20 j] bf16
  int j0 = m, j1 = 16 + m;
  if (kh == 1) {
    #pragma unroll
    for (int ti = 0; ti < 3; ++ti) {
      #pragma unroll
      for (int r = 0; r < 4; ++r) {
        int p = gV[ti] * 16 + hi * 4 + r;
        *(ushort*)(sm + OF_BASE + p * 40 + j0 * 2) = f2bf(oacc[ti][0][r]);
        if (m < 2)
          *(ushort*)(sm + OF_BASE + p * 40 + j1 * 2) = f2bf(oacc[ti][1][r]);
      }
    }
  }
  __syncthreads();
  if (kh == 0) {
    float bo0 = b_off[j0];
    float bo1 = (m < 2) ? b_off[j1] : 0.f;
    #pragma unroll
    for (int ti = 0; ti < 3; ++ti) {
      #pragma unroll
      for (int r = 0; r < 4; ++r) {
        int p = gV[ti] * 16 + hi * 4 + r;
        ushort* a0p = (ushort*)(sm + OF_BASE + p * 40 + j0 * 2);
        *a0p = f2bf(oacc[ti][0][r] + bf2f(*a0p) + bo0);
        if (m < 2) {
          ushort* a1p = (ushort*)(sm + OF_BASE + p * 40 + j1 * 2);
          *a1p = f2bf(oacc[ti][1][r] + bf2f(*a1p) + bo1);
        }
      }
    }
  }
  // stage wtb k=0 into dbuf slot 0 (overwrites wob region; phase A done)
  if (tid < 512) {
    int o = tid >> 3, c16 = tid & 7;
    uint4 v = *(const uint4*)(wtb + o * 64 + c16 * 8);
    *(uint4*)(sm + WS_BASE + o * 144 + c16 * 16) = v;
  }
  __syncthreads();

  // ---------------- Phase B: deform loop from LDS --------------------------
  f32x4 acc[3][4];
  #pragma unroll
  for (int ti = 0; ti < 3; ++ti)
    #pragma unroll
    for (int nt = 0; nt < 4; ++nt) acc[ti][nt] = (f32x4){0.f, 0.f, 0.f, 0.f};

  for (int k = 0; k < 9; ++k) {
    if (k < 8 && tid < 512) {    // prefetch next tap's w_def into other slot
      int o = tid >> 3, c16 = tid & 7;
      uint4 v = *(const uint4*)(wtb + (k + 1) * 4096 + o * 64 + c16 * 8);
      *(uint4*)(sm + WS_BASE + ((k + 1) & 1) * 9216 + o * 144 + c16 * 16) = v;
    }
    int ky = k / 3 - 1, kx = (k - (k / 3) * 3) - 1;
    const char* wkb = sm + WS_BASE + (k & 1) * 9216;
    bf16x8 bf0 = *(const bf16x8*)(wkb + m * 144 + hiB + khB);
    bf16x8 bf1 = *(const bf16x8*)(wkb + (16 + m) * 144 + hiB + khB);
    bf16x8 bf2 = *(const bf16x8*)(wkb + (32 + m) * 144 + hiB + khB);
    bf16x8 bf3 = *(const bf16x8*)(wkb + (48 + m) * 144 + hiB + khB);

    #pragma unroll
    for (int ti = 0; ti < 3; ++ti) {
      uint dd = *(const uint*)(sm + OF_BASE + pPix[ti] * 40 + k * 4);
      float dy = bflo(dd), dx = bfhi(dd);
      float py = (float)(hA[ti] + ky) + dy;
      float px = (float)(wAc[ti] + kx) + dx;
      float y0f = floorf(py), x0f = floorf(px);
      float ly = py - y0f, lx = px - x0f;
      int y0 = (int)y0f, x0 = (int)x0f;
      int y1 = y0 + 1, x1 = x0 + 1;
      float fy0 = (y0 >= 0 && y0 < Hh) ? 1.f : 0.f;
      float fy1 = (y1 >= 0 && y1 < Hh) ? 1.f : 0.f;
      float fx0 = (x0 >= 0 && x0 < Ww) ? 1.f : 0.f;
      float fx1 = (x1 >= 0 && x1 < Ww) ? 1.f : 0.f;
      int cy0 = min(max(y0, 0), 95), cy1 = min(max(y1, 0), 95);
      int cx0 = min(max(x0, 0), 95), cx1 = min(max(x1, 0), 95);
      int sy0 = min(max(cy0 - r0 + 3, 0), 8);
      int sy1 = min(max(cy1 - r0 + 3, 0), 8);
      const char* row0 = sm + sy0 * XS_ROW;
      const char* row1 = sm + sy1 * XS_ROW;
      uint4 c00 = *(const uint4*)(row0 + cx0 * 144 + hiB + khB);
      uint4 c01 = *(const uint4*)(row0 + cx1 * 144 + hiB + khB);
      uint4 c10 = *(const uint4*)(row1 + cx0 * 144 + hiB + khB);
      uint4 c11 = *(const uint4*)(row1 + cx1 * 144 + hiB + khB);
      float w00 = (1.f - ly) * (1.f - lx) * (fy0 * fx0);
      float w01 = (1.f - ly) * lx * (fy0 * fx1);
      float w10 = ly * (1.f - lx) * (fy1 * fx0);
      float w11 = ly * lx * (fy1 * fx1);
      uint ua[4];
      ua[0] = interp_pack(c00.x, c01.x, c10.x, c11.x, w00, w01, w10, w11);
      ua[1] = interp_pack(c00.y, c01.y, c10.y, c11.y, w00, w01, w10, w11);
      ua[2] = interp_pack(c00.z, c01.z, c10.z, c11.z, w00, w01, w10, w11);
      ua[3] = interp_pack(c00.w, c01.w, c10.w, c11.w, w00, w01, w10, w11);
      bf16x8 av;
      __builtin_memcpy(&av, ua, 16);
      acc[ti][0] = __builtin_amdgcn_mfma_f32_16x16x32_bf16(av, bf0, acc[ti][0], 0, 0, 0);
      acc[ti][1] = __builtin_amdgcn_mfma_f32_16x16x32_bf16(av, bf1, acc[ti][1], 0, 0, 0);
      acc[ti][2] = __builtin_amdgcn_mfma_f32_16x16x32_bf16(av, bf2, acc[ti][2], 0, 0, 0);
      acc[ti][3] = __builtin_amdgcn_mfma_f32_16x16x32_bf16(av, bf3, acc[ti][3], 0, 0, 0);
    }
    __syncthreads();
  }

  // ---------------- epilogue: transpose via LDS (alias xs), store + BN -----
  float* T = (float*)sm;     // [64][289] f32
  if (kh == 1) {
    #pragma unroll
    for (int ti = 0; ti < 3; ++ti)
      #pragma unroll
      for (int nt = 0; nt < 4; ++nt) {
        int o = nt * 16 + m;
        #pragma unroll
        for (int r = 0; r < 4; ++r) {
          int p = gV[ti] * 16 + hi * 4 + r;
          T[o * 289 + p] = acc[ti][nt][r];
        }
      }
  }
  __syncthreads();
  if (kh == 0) {
    float bd[4];
    bd[0] = b_def[m]; bd[1] = b_def[16 + m];
    bd[2] = b_def[32 + m]; bd[3] = b_def[48 + m];
    #pragma unroll
    for (int ti = 0; ti < 3; ++ti)
      #pragma unroll
      for (int nt = 0; nt < 4; ++nt) {
        int o = nt * 16 + m;
        #pragma unroll
        for (int r = 0; r < 4; ++r) {
          int p = gV[ti] * 16 + hi * 4 + r;
          T[o * 289 + p] += acc[ti][nt][r] + bd[nt];
        }
      }
  }
  __syncthreads();
  if (tid < 512) {
    int o = tid >> 3, seg = tid & 7;
    const float* Tr = T + o * 289 + seg * 36;
    float* og = out + ((size_t)(b * 64 + o)) * HW + rt * 288 + seg * 36;
    float s = 0.f, ss = 0.f;
    #pragma unroll
    for (int j4 = 0; j4 < 9; ++j4) {
      float4 v;
      v.x = Tr[j4 * 4 + 0]; v.y = Tr[j4 * 4 + 1];
      v.z = Tr[j4 * 4 + 2]; v.w = Tr[j4 * 4 + 3];
      s += v.x + v.y + v.z + v.w;
      ss += v.x * v.x + v.y * v.y + v.z * v.z + v.w * v.w;
      *(float4*)(og + j4 * 4) = v;
    }
    s += __shfl_down(s, 4); s += __shfl_down(s, 2); s += __shfl_down(s, 1);
    ss += __shfl_down(ss, 4); ss += __shfl_down(ss, 2); ss += __shfl_down(ss, 1);
    if ((tid & 7) == 0) {
      parts[o * 256 + bid] = s;
      parts[16384 + o * 256 + bid] = ss;
    }
  }
}

// ---------------------------------------------------------------------------
// K3: finalize BN scale/shift.  64 blocks x 256 threads.
// ---------------------------------------------------------------------------
__global__ __launch_bounds__(256) void k_stats(
    const float* __restrict__ parts, const float* __restrict__ gamma,
    const float* __restrict__ beta, float* __restrict__ stats)
{
  int c = blockIdx.x;
  int tid = threadIdx.x;
  float s = 0.f, ss = 0.f;
  for (int i = tid; i < 256; i += 256) {
    s += parts[c * 256 + i];
    ss += parts[16384 + c * 256 + i];
  }
  #pragma unroll
  for (int off = 32; off >= 1; off >>= 1) {
    s += __shfl_down(s, off);
    ss += __shfl_down(ss, off);
  }
  __shared__ float rs[4], rss[4];
  int wave = tid >> 6, lane = tid & 63;
  if (lane == 0) { rs[wave] = s; rss[wave] = ss; }
  __syncthreads();
  if (tid == 0) {
    float S1 = rs[0] + rs[1] + rs[2] + rs[3];
    float S2 = rss[0] + rss[1] + rss[2] + rss[3];
    const float inv = 1.f / 73728.f;
    float mean = S1 * inv;
    float var = S2 * inv - mean * mean;
    float scale = gamma[c] * rsqrtf(var + 1e-5f);
    stats[c] = scale;
    stats[64 + c] = beta[c] - mean * scale;
  }
}

// ---------------------------------------------------------------------------
// K4: in-place normalize + affine + relu, float4 vectorized.
// ---------------------------------------------------------------------------
__global__ __launch_bounds__(256) void k_norm(
    float* __restrict__ out, const float* __restrict__ stats)
{
  int g = blockIdx.x * 256 + threadIdx.x;
  int o = (g / 2304) & 63;
  float sc = stats[o], sh = stats[64 + o];
  float4 v = ((const float4*)out)[g];
  v.x = fmaxf(fmaf(v.x, sc, sh), 0.f);
  v.y = fmaxf(fmaf(v.y, sc, sh), 0.f);
  v.z = fmaxf(fmaf(v.z, sc, sh), 0.f);
  v.w = fmaxf(fmaf(v.w, sc, sh), 0.f);
  ((float4*)out)[g] = v;
}

extern "C" void kernel_launch(void* const* d_in, const int* in_sizes, int n_in,
                              void* d_out, int out_size, void* d_ws, size_t ws_size,
                              hipStream_t stream) {
  const float* x     = (const float*)d_in[0];
  const float* w_off = (const float*)d_in[1];
  const float* b_off = (const float*)d_in[2];
  const float* w_def = (const float*)d_in[3];
  const float* b_def = (const float*)d_in[4];
  const float* gamma = (const float*)d_in[5];
  const float* beta  = (const float*)d_in[6];
  float* out = (float*)d_out;

  // workspace layout (float slots): wtb | wob | xt | parts | stats
  float* base  = (float*)d_ws;
  ushort* wtb  = (ushort*)base;                    // 36864 bf16 (18432 slots)
  ushort* wob  = (ushort*)(base + 18432);          // 18432 bf16 (9216 slots)
  ushort* xt   = (ushort*)(base + 18432 + 9216);   // 4718592 bf16 (2359296 slots)
  float* parts = base + 18432 + 9216 + 2359296;    // 32768
  float* stats = parts + 32768;                    // 128

  (void)hipFuncSetAttribute((const void*)k_main,
      hipFuncAttributeMaxDynamicSharedMemorySize, SM_TOTAL);

  k_xt<<<1152, 256, 0, stream>>>(x, w_def, w_off, xt, wtb, wob);
  k_main<<<256, 768, SM_TOTAL, stream>>>(xt, wtb, wob, b_off, b_def, out, parts);
  k_stats<<<64, 256, 0, stream>>>(parts, gamma, beta, stats);
  k_norm<<<4608, 256, 0, stream>>>(out, stats);
}